// Round 10
// baseline (1147.231 us; speedup 1.0000x reference)
//
#include <hip/hip_runtime.h>
#include <math.h>

namespace {

constexpr int TSEQ   = 2048;
constexpr int DIN    = 16;
constexpr int NH1    = 5;
constexpr int NH2    = 50;
constexpr int NCLS   = 20;
constexpr int CHUNK  = 64;
constexpr int NCHUNK = TSEQ / CHUNK;
constexpr int BATCH  = 256;

typedef __attribute__((ext_vector_type(2))) float f32x2;

// No clamp: exp(+inf)->inf, rcp(inf)->0 — still correct; inputs bounded.
__device__ __forceinline__ float fast_sigm(float x) {
    return __fdividef(1.f, 1.f + __expf(-x));
}
// tanh(x) = 2*sigm(2x) - 1
__device__ __forceinline__ float fast_tanh(float x) {
    return fmaf(2.f, fast_sigm(2.f * x), -1.f);
}

// quad_perm DPP: VALU-speed cross-lane within aligned quads.
template <int CTRL>
__device__ __forceinline__ float qperm(float v) {
    int i = __builtin_bit_cast(int, v);
    int r = __builtin_amdgcn_update_dpp(i, i, CTRL, 0xf, 0xf, false);
    return __builtin_bit_cast(float, r);
}
__device__ __forceinline__ float rdlane(float v, int lane) {
    return __builtin_bit_cast(float,
        __builtin_amdgcn_readlane(__builtin_bit_cast(int, v), lane));
}
// splat-scalar packed FMA: acc += {s,s} * w  (targets v_pk_fma_f32)
__device__ __forceinline__ f32x2 pkfma(float s, f32x2 w, f32x2 acc) {
    f32x2 ss; ss.x = s; ss.y = s;
    return __builtin_elementwise_fma(ss, w, acc);
}

// R8c: ONE-WAVE L2 (third submit; R8/R8b hit "container failed twice" infra
// errors — kernel audited hang/OOB-clean both times). Hedge vs the one
// configuration novelty: restore the known-good 256-thread block from
// R0-R7. Waves 2-3 are pure barrier companions (33 syncthreads, no work).
//
// Structure: lane u of wave 0 owns unit u with ALL 4 gates -> h2 lives
// entirely in registers (lane u's output IS h2[u]); the 50-wide broadcast
// is 50 v_readlane; the 200 row-FMAs become 100 v_pk_fma_f32. ZERO per-step
// barriers / LDS exchange — the only sync is the L1 producer handoff, once
// per 64-step chunk. Wave 1 = L1 producer + x stager (R3's proven role).
__global__ __launch_bounds__(256, 1) void lstm_fused_kernel(
    const float* __restrict__ x,     // (256,2048,16)
    const float* __restrict__ W1ih,  // (20,16)
    const float* __restrict__ W1hh,  // (20,5)
    const float* __restrict__ b1ih,  // (20)
    const float* __restrict__ b1hh,  // (20)
    const float* __restrict__ W2ih,  // (200,5)
    const float* __restrict__ W2hh,  // (200,50)
    const float* __restrict__ b2ih,  // (200)
    const float* __restrict__ b2hh,  // (200)
    const float* __restrict__ Wfc,   // (20,50)
    const float* __restrict__ bfc,   // (20)
    float* __restrict__ out)         // result(256,20) ++ last(256,50)
{
    const int b    = blockIdx.x;
    const int tid  = threadIdx.x;
    const int lane = tid & 63;
    const int wv   = tid >> 6;   // 0 = L2 consumer, 1 = L1 producer, 2/3 idle

    __shared__ __align__(16) float s_x[2][CHUNK * DIN];   // x dbuf (8 KB)
    __shared__ __align__(16) float s_h1[2][CHUNK][8];     // h1 stream dbuf (4 KB)

    const float* xb = x + (size_t)b * TSEQ * DIN;

    if (wv >= 2) {
        // ============ waves 2/3: barrier companions (no work) ============
        __syncthreads();                                // prologue barrier
        #pragma unroll 1
        for (int c = 0; c < NCHUNK; ++c)
            __syncthreads();                            // chunk barriers
    } else if (wv == 1) {
        // ================= wave 1: L1 producer + x stager =================
        const int r1 = (lane < NCLS) ? ((lane & 3) * NH1 + (lane >> 2)) : 0;
        float w1h[NH1], w1x[DIN];
        #pragma unroll
        for (int j = 0; j < NH1; ++j) w1h[j] = W1hh[r1 * NH1 + j];
        #pragma unroll
        for (int d = 0; d < DIN; ++d) w1x[d] = W1ih[r1 * DIN + d];
        const float bias1 = b1ih[r1] + b1hh[r1];
        const bool  isg1  = ((lane & 3) == 2) && (lane < NCLS);
        const float isc1  = isg1 ? 2.f : 1.f;
        const float osc1  = isg1 ? 2.f : 1.f;
        const float off1  = isg1 ? -1.f : 0.f;
        float c1 = 0.f;
        float sh0v = 0.f, sh1v = 0.f, sh2v = 0.f, sh3v = 0.f, sh4v = 0.f;
        float4 xr0, xr1, xr2, xr3;

        // tree-structured dot to shorten the producer's serial chain
        auto l1_prod = [&](const float* xs, float* h1out) {
            float4 xv0 = *(const float4*)(xs + 0);
            float4 xv1 = *(const float4*)(xs + 4);
            float4 xv2 = *(const float4*)(xs + 8);
            float4 xv3 = *(const float4*)(xs + 12);
            float sa = fmaf(xv0.y, w1x[1],  xv0.x * w1x[0]);
            sa = fmaf(xv0.z, w1x[2], sa);  sa = fmaf(xv0.w, w1x[3], sa);
            float sb = fmaf(xv1.y, w1x[5],  xv1.x * w1x[4]);
            sb = fmaf(xv1.z, w1x[6], sb);  sb = fmaf(xv1.w, w1x[7], sb);
            float sc = fmaf(xv2.y, w1x[9],  xv2.x * w1x[8]);
            sc = fmaf(xv2.z, w1x[10], sc); sc = fmaf(xv2.w, w1x[11], sc);
            float sd = fmaf(xv3.y, w1x[13], xv3.x * w1x[12]);
            sd = fmaf(xv3.z, w1x[14], sd); sd = fmaf(xv3.w, w1x[15], sd);
            float ha = fmaf(sh1v, w1h[1], sh0v * w1h[0]);
            ha = fmaf(sh2v, w1h[2], ha);
            float hb = fmaf(sh4v, w1h[4], sh3v * w1h[3]);
            float g1 = ((sa + sb) + (sc + sd)) + ((ha + hb) + bias1);
            float act = fmaf(osc1, fast_sigm(isc1 * g1), off1);
            float f_ = qperm<0xB1>(act);
            float gg = qperm<0x4E>(act);
            float o_ = qperm<0x1B>(act);
            c1 = fmaf(f_, c1, act * gg);            // valid on lanes 4j+0
            float h1me = o_ * fast_tanh(c1);
            sh0v = rdlane(h1me, 0);  sh1v = rdlane(h1me, 4);
            sh2v = rdlane(h1me, 8);  sh3v = rdlane(h1me, 12);
            sh4v = rdlane(h1me, 16);
            if ((lane & 3) == 0 && lane < NCLS) h1out[lane >> 2] = h1me;
        };

        // prologue: stage chunk0, run L1 chunk0, stage chunk1, preload chunk2
        xr0 = ((const float4*)(xb))[lane];
        xr1 = ((const float4*)(xb + 256))[lane];
        xr2 = ((const float4*)(xb + 512))[lane];
        xr3 = ((const float4*)(xb + 768))[lane];
        ((float4*)s_x[0])[lane]       = xr0;
        ((float4*)s_x[0])[64 + lane]  = xr1;
        ((float4*)s_x[0])[128 + lane] = xr2;
        ((float4*)s_x[0])[192 + lane] = xr3;
        for (int t = 0; t < CHUNK; ++t)
            l1_prod(&s_x[0][t * DIN], &s_h1[0][t][0]);
        xr0 = ((const float4*)(xb + 1024))[lane];
        xr1 = ((const float4*)(xb + 1280))[lane];
        xr2 = ((const float4*)(xb + 1536))[lane];
        xr3 = ((const float4*)(xb + 1792))[lane];
        ((float4*)s_x[1])[lane]       = xr0;
        ((float4*)s_x[1])[64 + lane]  = xr1;
        ((float4*)s_x[1])[128 + lane] = xr2;
        ((float4*)s_x[1])[192 + lane] = xr3;
        xr0 = ((const float4*)(xb + 2048))[lane];
        xr1 = ((const float4*)(xb + 2304))[lane];
        xr2 = ((const float4*)(xb + 2560))[lane];
        xr3 = ((const float4*)(xb + 2816))[lane];
        __syncthreads();                                // prologue barrier

        #pragma unroll 1
        for (int c = 0; c < NCHUNK; ++c) {
            if (c + 2 < NCHUNK) {
                // land staged x (chunk c+2) into s_x[c&1]; kick loads for c+3
                ((float4*)s_x[c & 1])[lane]       = xr0;
                ((float4*)s_x[c & 1])[64 + lane]  = xr1;
                ((float4*)s_x[c & 1])[128 + lane] = xr2;
                ((float4*)s_x[c & 1])[192 + lane] = xr3;
                if (c + 3 < NCHUNK) {
                    const float* xc = xb + (size_t)(c + 3) * (CHUNK * DIN);
                    xr0 = ((const float4*)(xc))[lane];
                    xr1 = ((const float4*)(xc + 256))[lane];
                    xr2 = ((const float4*)(xc + 512))[lane];
                    xr3 = ((const float4*)(xc + 768))[lane];
                }
            }
            if (c + 1 < NCHUNK) {
                // produce h1 for chunk c+1 into buffer (c+1)&1 — runs far
                // ahead of the consumer (~10k cy of work in a ~30k cy chunk)
                #pragma unroll 1
                for (int t = 0; t < CHUNK; ++t)
                    l1_prod(&s_x[(c & 1) ^ 1][t * DIN], &s_h1[(c + 1) & 1][t][0]);
            }
            __syncthreads();                            // chunk barrier
        }
    } else {
        // ================= wave 0: one-wave L2 ===========================
        const int  u  = lane;
        const bool on = (u < NH2);

        // recurrent weights, gate-paired: wif[k]={Wi[u][k],Wf[u][k]},
        // wgo[k]={Wg[u][k],Wo[u][k]}  (200 VGPRs; 1 wave/SIMD budget = 512)
        f32x2 wif[NH2], wgo[NH2];
        #pragma unroll
        for (int k = 0; k < NH2; ++k) {
            if (on) {
                wif[k].x = W2hh[(0 * NH2 + u) * NH2 + k];
                wif[k].y = W2hh[(1 * NH2 + u) * NH2 + k];
                wgo[k].x = W2hh[(2 * NH2 + u) * NH2 + k];
                wgo[k].y = W2hh[(3 * NH2 + u) * NH2 + k];
            } else {
                wif[k].x = 0.f; wif[k].y = 0.f;
                wgo[k].x = 0.f; wgo[k].y = 0.f;
            }
        }
        f32x2 w2iif[NH1], w2igo[NH1], b2if, b2go;
        if (on) {
            #pragma unroll
            for (int d = 0; d < NH1; ++d) {
                w2iif[d].x = W2ih[(0 * NH2 + u) * NH1 + d];
                w2iif[d].y = W2ih[(1 * NH2 + u) * NH1 + d];
                w2igo[d].x = W2ih[(2 * NH2 + u) * NH1 + d];
                w2igo[d].y = W2ih[(3 * NH2 + u) * NH1 + d];
            }
            b2if.x = b2ih[0 * NH2 + u] + b2hh[0 * NH2 + u];
            b2if.y = b2ih[1 * NH2 + u] + b2hh[1 * NH2 + u];
            b2go.x = b2ih[2 * NH2 + u] + b2hh[2 * NH2 + u];
            b2go.y = b2ih[3 * NH2 + u] + b2hh[3 * NH2 + u];
        } else {
            #pragma unroll
            for (int d = 0; d < NH1; ++d) {
                w2iif[d].x = 0.f; w2iif[d].y = 0.f;
                w2igo[d].x = 0.f; w2igo[d].y = 0.f;
            }
            b2if.x = 0.f; b2if.y = 0.f; b2go.x = 0.f; b2go.y = 0.f;
        }

        float h2v = 0.f;     // lane u holds h2[u] — the state never leaves regs
        float c2  = 0.f;
        float4 h1a; float h1e;

        __syncthreads();                                // prologue barrier
        h1a = *(const float4*)&s_h1[0][0][0];           // h1(t=0), post-barrier
        h1e = s_h1[0][0][4];

        #pragma unroll 1
        for (int c = 0; c < NCHUNK; ++c) {
            const int cb = c & 1;
            #pragma unroll 1
            for (int t = 0; t < CHUNK; ++t) {
                // x-side gate pre-activations from carried h1 regs
                f32x2 xif = b2if, xgo = b2go;
                xif = pkfma(h1a.x, w2iif[0], xif);  xgo = pkfma(h1a.x, w2igo[0], xgo);
                xif = pkfma(h1a.y, w2iif[1], xif);  xgo = pkfma(h1a.y, w2igo[1], xgo);
                xif = pkfma(h1a.z, w2iif[2], xif);  xgo = pkfma(h1a.z, w2igo[2], xgo);
                xif = pkfma(h1a.w, w2iif[3], xif);  xgo = pkfma(h1a.w, w2igo[3], xgo);
                xif = pkfma(h1e,  w2iif[4], xif);   xgo = pkfma(h1e,  w2igo[4], xgo);

                // prefetch next-step h1 (uniform addr; t=63 value is dummy,
                // replaced by the post-barrier cross-chunk load)
                const int tn = (t + 1) & (CHUNK - 1);
                h1a = *(const float4*)&s_h1[cb][tn][0];
                h1e = s_h1[cb][tn][4];

                // recurrent matvec: readlane broadcast + packed FMA,
                // even/odd dual chains for FMA-latency cover
                f32x2 a0 = {0.f, 0.f}, a1 = {0.f, 0.f};
                f32x2 g0 = {0.f, 0.f}, g1 = {0.f, 0.f};
                #pragma unroll
                for (int k = 0; k < NH2; k += 2) {
                    const float s0 = rdlane(h2v, k);
                    const float s1 = rdlane(h2v, k + 1);
                    a0 = pkfma(s0, wif[k],     a0);
                    g0 = pkfma(s0, wgo[k],     g0);
                    a1 = pkfma(s1, wif[k + 1], a1);
                    g1 = pkfma(s1, wgo[k + 1], g1);
                }
                const f32x2 pif = (a0 + a1) + xif;
                const f32x2 pgo = (g0 + g1) + xgo;

                const float i_ = fast_sigm(pif.x);
                const float f_ = fast_sigm(pif.y);
                const float g_ = fast_tanh(pgo.x);
                const float o_ = fast_sigm(pgo.y);
                c2  = fmaf(f_, c2, i_ * g_);
                h2v = o_ * fast_tanh(c2);
            }
            __syncthreads();                            // chunk barrier
            if (c + 1 < NCHUNK) {                       // formally-ordered
                h1a = *(const float4*)&s_h1[(c + 1) & 1][0][0];
                h1e = s_h1[(c + 1) & 1][0][4];
            }
        }

        // ---- outputs: result(256,20) @0, last(256,50) @5120 ----
        if (on) out[BATCH * NCLS + b * NH2 + u] = h2v;
        {
            const int row = (lane < NCLS) ? lane : 0;
            float acc = bfc[row];
            const float* wr = Wfc + row * NH2;
            #pragma unroll
            for (int j = 0; j < NH2; ++j)
                acc = fmaf(rdlane(h2v, j), wr[j], acc);
            if (lane < NCLS) out[b * NCLS + lane] = acc;
        }
    }
}

} // namespace

extern "C" void kernel_launch(void* const* d_in, const int* in_sizes, int n_in,
                              void* d_out, int out_size, void* d_ws, size_t ws_size,
                              hipStream_t stream) {
    (void)in_sizes; (void)n_in; (void)d_ws; (void)ws_size; (void)out_size;
    const float* x    = (const float*)d_in[0];
    const float* W1ih = (const float*)d_in[1];
    const float* W1hh = (const float*)d_in[2];
    const float* b1ih = (const float*)d_in[3];
    const float* b1hh = (const float*)d_in[4];
    const float* W2ih = (const float*)d_in[5];
    const float* W2hh = (const float*)d_in[6];
    const float* b2ih = (const float*)d_in[7];
    const float* b2hh = (const float*)d_in[8];
    const float* Wfc  = (const float*)d_in[9];
    const float* bfc  = (const float*)d_in[10];

    lstm_fused_kernel<<<dim3(BATCH), dim3(256), 0, stream>>>(
        x, W1ih, W1hh, b1ih, b1hh, W2ih, W2hh, b2ih, b2hh, Wfc, bfc,
        (float*)d_out);
}

// Round 11
// 952.655 us; speedup vs baseline: 1.2042x; 1.2042x over previous
//
#include <hip/hip_runtime.h>
#include <math.h>

namespace {

constexpr int TSEQ   = 2048;
constexpr int DIN    = 16;
constexpr int NH1    = 5;
constexpr int NH2    = 50;
constexpr int NCLS   = 20;
constexpr int CHUNK  = 64;
constexpr int NCHUNK = TSEQ / CHUNK;
constexpr int BATCH  = 256;
constexpr int GSTR   = 80;          // padded gate-row stride: 80 mod 32 = 16 -> 2-way (free)
constexpr int PROW   = 4 * GSTR;    // 320 floats per (buf,wave) partial region
constexpr int BUFF   = 2 * PROW;    // 640 floats per buf (2 L2 waves)

typedef __attribute__((ext_vector_type(2))) float f32x2;

// No clamp: exp(+inf)->inf, rcp(inf)->0 — still correct; inputs bounded.
__device__ __forceinline__ float fast_sigm(float x) {
    return __fdividef(1.f, 1.f + __expf(-x));
}
// tanh(x) = 2*sigm(2x) - 1
__device__ __forceinline__ float fast_tanh(float x) {
    return fmaf(2.f, fast_sigm(2.f * x), -1.f);
}

// quad_perm DPP: VALU-speed cross-lane within aligned quads.
template <int CTRL>
__device__ __forceinline__ float qperm(float v) {
    int i = __builtin_bit_cast(int, v);
    int r = __builtin_amdgcn_update_dpp(i, i, CTRL, 0xf, 0xf, false);
    return __builtin_bit_cast(float, r);
}
__device__ __forceinline__ float rdlane(float v, int lane) {
    return __builtin_bit_cast(float,
        __builtin_amdgcn_readlane(__builtin_bit_cast(int, v), lane));
}
// splat-scalar packed FMA: acc += {s,s} * w  (targets v_pk_fma_f32)
__device__ __forceinline__ f32x2 pkfma(float s, f32x2 w, f32x2 acc) {
    f32x2 ss; ss.x = s; ss.y = s;
    return __builtin_elementwise_fma(ss, w, acc);
}

// Producer-only barrier: LDS-drain + s_barrier, NO vmcnt drain, so the L1
// wave's global x prefetch stays in flight across step barriers. L2 waves
// use plain __syncthreads() (R2 lesson). Barrier counts match across roles.
#define W4_BARRIER() asm volatile("s_waitcnt lgkmcnt(0)\n\ts_barrier" ::: "memory")

// R11: R3's split-K exchange, narrowed. 3 waves (one per SIMD, no sharing):
//   wave 0/1: L2 split-K, K-slice=25 each (offs {0,25}); partial FMAs packed
//             as v_pk_fma_f32 over row pairs (50 pk ops vs 100 scalar);
//             combine covers 25 units/wave: primary unit OFF+ul (ul 0..15)
//             plus secondary OFF+16+ul (ul<9) — second unit's act chain is
//             independent ILP hidden under the first's transcendentals.
//   wave 2:   L1 producer + x stager (R3's wave-4, verbatim).
// Gather = 2 reads (was 4); rendezvous = 3 waves (was 5, with SIMD0 shared).
// R5/R6/R8 lesson honored: the K-reduction stays split and pre-barrier.
__global__ __launch_bounds__(192, 1) void lstm_fused_kernel(
    const float* __restrict__ x,     // (256,2048,16)
    const float* __restrict__ W1ih,  // (20,16)
    const float* __restrict__ W1hh,  // (20,5)
    const float* __restrict__ b1ih,  // (20)
    const float* __restrict__ b1hh,  // (20)
    const float* __restrict__ W2ih,  // (200,5)
    const float* __restrict__ W2hh,  // (200,50)
    const float* __restrict__ b2ih,  // (200)
    const float* __restrict__ b2hh,  // (200)
    const float* __restrict__ Wfc,   // (20,50)
    const float* __restrict__ bfc,   // (20)
    float* __restrict__ out)         // result(256,20) ++ last(256,50)
{
    const int b    = blockIdx.x;
    const int tid  = threadIdx.x;
    const int lane = tid & 63;
    const int wv   = tid >> 6;       // 0,1 = L2 split-K; 2 = L1 producer

    __shared__ __align__(16) float s_x[2][CHUNK * DIN];   // x dbuf (8 KB)
    __shared__ __align__(16) float s_part[2][2][PROW];    // partials dbuf (5 KB)
    __shared__ __align__(16) float s_h1[2][CHUNK][8];     // h1 stream dbuf (4 KB)
    __shared__ float s_h2[NH2];                           // final-h2 mirror

    const float* xb = x + (size_t)b * TSEQ * DIN;

    if (wv == 2) {
        // ================= wave 2: L1 producer + x stager =================
        const int r1 = (lane < NCLS) ? ((lane & 3) * NH1 + (lane >> 2)) : 0;
        float w1h[NH1], w1x[DIN];
        #pragma unroll
        for (int j = 0; j < NH1; ++j) w1h[j] = W1hh[r1 * NH1 + j];
        #pragma unroll
        for (int d = 0; d < DIN; ++d) w1x[d] = W1ih[r1 * DIN + d];
        const float bias1 = b1ih[r1] + b1hh[r1];
        const bool  isg1  = ((lane & 3) == 2) && (lane < NCLS);
        const float isc1  = isg1 ? 2.f : 1.f;
        const float osc1  = isg1 ? 2.f : 1.f;
        const float off1  = isg1 ? -1.f : 0.f;
        float c1 = 0.f;
        float sh0v = 0.f, sh1v = 0.f, sh2v = 0.f, sh3v = 0.f, sh4v = 0.f;
        float4 xr0, xr1, xr2, xr3;

        auto l1_prod = [&](const float* xs, float* h1out) {
            float4 xv0 = *(const float4*)(xs + 0);
            float4 xv1 = *(const float4*)(xs + 4);
            float4 xv2 = *(const float4*)(xs + 8);
            float4 xv3 = *(const float4*)(xs + 12);
            float sa = fmaf(xv0.y, w1x[1],  xv0.x * w1x[0]);
            sa = fmaf(xv0.z, w1x[2], sa);  sa = fmaf(xv0.w, w1x[3], sa);
            float sb = fmaf(xv1.y, w1x[5],  xv1.x * w1x[4]);
            sb = fmaf(xv1.z, w1x[6], sb);  sb = fmaf(xv1.w, w1x[7], sb);
            float sc = fmaf(xv2.y, w1x[9],  xv2.x * w1x[8]);
            sc = fmaf(xv2.z, w1x[10], sc); sc = fmaf(xv2.w, w1x[11], sc);
            float sd = fmaf(xv3.y, w1x[13], xv3.x * w1x[12]);
            sd = fmaf(xv3.z, w1x[14], sd); sd = fmaf(xv3.w, w1x[15], sd);
            float ha = fmaf(sh1v, w1h[1], sh0v * w1h[0]);
            ha = fmaf(sh2v, w1h[2], ha);
            float hb = fmaf(sh4v, w1h[4], sh3v * w1h[3]);
            float g1 = ((sa + sb) + (sc + sd)) + ((ha + hb) + bias1);
            float act = fmaf(osc1, fast_sigm(isc1 * g1), off1);
            float f_ = qperm<0xB1>(act);
            float gg = qperm<0x4E>(act);
            float o_ = qperm<0x1B>(act);
            c1 = fmaf(f_, c1, act * gg);            // valid on lanes 4j+0
            float h1me = o_ * fast_tanh(c1);
            sh0v = rdlane(h1me, 0);  sh1v = rdlane(h1me, 4);
            sh2v = rdlane(h1me, 8);  sh3v = rdlane(h1me, 12);
            sh4v = rdlane(h1me, 16);
            if ((lane & 3) == 0 && lane < NCLS) h1out[lane >> 2] = h1me;
        };

        // prologue: stage chunk0, run L1 chunk0, stage chunk1, preload chunk2
        xr0 = ((const float4*)(xb))[lane];
        xr1 = ((const float4*)(xb + 256))[lane];
        xr2 = ((const float4*)(xb + 512))[lane];
        xr3 = ((const float4*)(xb + 768))[lane];
        ((float4*)s_x[0])[lane]       = xr0;
        ((float4*)s_x[0])[64 + lane]  = xr1;
        ((float4*)s_x[0])[128 + lane] = xr2;
        ((float4*)s_x[0])[192 + lane] = xr3;
        for (int t = 0; t < CHUNK; ++t)
            l1_prod(&s_x[0][t * DIN], &s_h1[0][t][0]);
        xr0 = ((const float4*)(xb + 1024))[lane];
        xr1 = ((const float4*)(xb + 1280))[lane];
        xr2 = ((const float4*)(xb + 1536))[lane];
        xr3 = ((const float4*)(xb + 1792))[lane];
        ((float4*)s_x[1])[lane]       = xr0;
        ((float4*)s_x[1])[64 + lane]  = xr1;
        ((float4*)s_x[1])[128 + lane] = xr2;
        ((float4*)s_x[1])[192 + lane] = xr3;
        xr0 = ((const float4*)(xb + 2048))[lane];
        xr1 = ((const float4*)(xb + 2304))[lane];
        xr2 = ((const float4*)(xb + 2560))[lane];
        xr3 = ((const float4*)(xb + 2816))[lane];
        W4_BARRIER();                                   // prologue barrier

        #pragma unroll 1
        for (int c = 0; c < NCHUNK; ++c) {
            const int  cur   = c & 1, nxt = cur ^ 1;
            const bool w4run = (c + 1 < NCHUNK);
            if (c + 2 < NCHUNK) {
                ((float4*)s_x[cur])[lane]       = xr0;
                ((float4*)s_x[cur])[64 + lane]  = xr1;
                ((float4*)s_x[cur])[128 + lane] = xr2;
                ((float4*)s_x[cur])[192 + lane] = xr3;
                if (c + 3 < NCHUNK) {
                    const float* xc = xb + (size_t)(c + 3) * (CHUNK * DIN);
                    xr0 = ((const float4*)(xc))[lane];
                    xr1 = ((const float4*)(xc + 256))[lane];
                    xr2 = ((const float4*)(xc + 512))[lane];
                    xr3 = ((const float4*)(xc + 768))[lane];
                }
            }
            #pragma unroll 1
            for (int tt = 0; tt < CHUNK; tt += 2) {
                if (w4run) l1_prod(&s_x[nxt][tt * DIN], &s_h1[nxt][tt][0]);
                W4_BARRIER();
                if (w4run) l1_prod(&s_x[nxt][(tt + 1) * DIN], &s_h1[nxt][tt + 1][0]);
                W4_BARRIER();
            }
        }
        __syncthreads();                                // join
    } else {
        // ================= waves 0/1: L2 split-K, CNT=25 ==================
        const int OFF = 25 * wv;                        // my K-slice / unit range

        // partial-phase weights, row-paired for v_pk_fma_f32:
        // lane owns padded rows 4*lane..4*lane+3 (same gate pg, units pu0..pu0+3)
        const int pr0 = 4 * lane;
        const int pg  = pr0 >> 6;
        const int pu0 = pr0 & 63;
        f32x2 wp01[25], wp23[25];
        #pragma unroll
        for (int kk = 0; kk < 25; ++kk) {
            const int k = OFF + kk;
            wp01[kk].x = (pu0 + 0 < NH2) ? W2hh[(pg * NH2 + pu0 + 0) * NH2 + k] : 0.f;
            wp01[kk].y = (pu0 + 1 < NH2) ? W2hh[(pg * NH2 + pu0 + 1) * NH2 + k] : 0.f;
            wp23[kk].x = (pu0 + 2 < NH2) ? W2hh[(pg * NH2 + pu0 + 2) * NH2 + k] : 0.f;
            wp23[kk].y = (pu0 + 3 < NH2) ? W2hh[(pg * NH2 + pu0 + 3) * NH2 + k] : 0.f;
        }

        // combine-phase: lane = 4*ul+g; primary unit u1=OFF+ul (all 16 valid),
        // secondary unit u2=OFF+16+ul (ul<9 only). x-gates packed {u1,u2}.
        const int  ul   = lane >> 2;
        const int  g    = lane & 3;
        const int  u1   = OFF + ul;
        const bool has2 = (ul < 9);
        const int  u2   = OFF + 16 + (has2 ? ul : 0);
        const int  rr1  = g * NH2 + u1;
        const int  rr2  = g * NH2 + u2;
        f32x2 w2i12[NH1], b2;
        #pragma unroll
        for (int d = 0; d < NH1; ++d) {
            w2i12[d].x = W2ih[rr1 * NH1 + d];
            w2i12[d].y = has2 ? W2ih[rr2 * NH1 + d] : 0.f;
        }
        b2.x = b2ih[rr1] + b2hh[rr1];
        b2.y = has2 ? (b2ih[rr2] + b2hh[rr2]) : 0.f;
        const bool  isg2 = (g == 2);
        const float isc2 = isg2 ? 2.f : 1.f;
        const float osc2 = isg2 ? 2.f : 1.f;
        const float off2 = isg2 ? -1.f : 0.f;

        // LDS pointers: write = conflict-free b128; gather = stride-80 rows
        float4* wpart = (float4*)(&s_part[0][wv][GSTR * (lane >> 4)]) + (lane & 15);
        const float* rpart = &s_part[0][0][g * GSTR + u1];  // +16 = unit2

        float hsl[25];                       // wave's h2 K-slice (SGPRs)
        #pragma unroll
        for (int k = 0; k < 25; ++k) hsl[k] = 0.f;
        float c2a = 0.f, c2b = 0.f;
        float4 h1a = make_float4(0.f, 0.f, 0.f, 0.f);
        float  h1e = 0.f;
        f32x2  xp12; xp12.x = 0.f; xp12.y = 0.f;

        __syncthreads();                                // prologue barrier

        #pragma unroll 1
        for (int c = 0; c < NCHUNK; ++c) {
            const int cur = c & 1;

            #define L2P(BUF, TT)                                           \
            {                                                              \
                const float* h1p = &s_h1[cur][TT][0];                      \
                h1a = *(const float4*)h1p;     /* uniform -> broadcast */  \
                h1e = h1p[4];                                              \
                xp12 = b2;                                                 \
                xp12 = pkfma(h1a.x, w2i12[0], xp12);                       \
                xp12 = pkfma(h1a.y, w2i12[1], xp12);                       \
                xp12 = pkfma(h1a.z, w2i12[2], xp12);                       \
                xp12 = pkfma(h1a.w, w2i12[3], xp12);                       \
                xp12 = pkfma(h1e,  w2i12[4], xp12);                        \
                f32x2 a01; a01.x = 0.f; a01.y = 0.f;                       \
                f32x2 a23; a23.x = 0.f; a23.y = 0.f;                       \
                _Pragma("unroll")                                          \
                for (int kk = 0; kk < 25; ++kk) {                          \
                    a01 = pkfma(hsl[kk], wp01[kk], a01);                   \
                    a23 = pkfma(hsl[kk], wp23[kk], a23);                   \
                }                                                          \
                wpart[(BUF) * (BUFF / 4)] = make_float4(a01.x, a01.y,      \
                                                        a23.x, a23.y);     \
            }

            #define L2C(BUF)                                               \
            {                                                              \
                const float* rb = rpart + (BUF) * BUFF;                    \
                const float p0 = rb[0];                                    \
                const float p1 = rb[PROW];                                 \
                const float q0 = rb[16];                                   \
                const float q1 = rb[PROW + 16];                            \
                float pre1 = (p0 + p1) + xp12.x;                           \
                float pre2 = (q0 + q1) + xp12.y;                           \
                float act1 = fmaf(osc2, fast_sigm(isc2 * pre1), off2);     \
                float act2 = fmaf(osc2, fast_sigm(isc2 * pre2), off2);     \
                float f1 = qperm<0xB1>(act1);                              \
                float g1 = qperm<0x4E>(act1);                              \
                float o1 = qperm<0x1B>(act1);                              \
                float f2 = qperm<0xB1>(act2);                              \
                float g2 = qperm<0x4E>(act2);                              \
                float o2 = qperm<0x1B>(act2);                              \
                c2a = fmaf(f1, c2a, act1 * g1);                            \
                c2b = fmaf(f2, c2b, act2 * g2);                            \
                float hn1 = o1 * fast_tanh(c2a);                           \
                float hn2 = o2 * fast_tanh(c2b);                           \
                _Pragma("unroll")                                          \
                for (int k = 0; k < 16; ++k) hsl[k] = rdlane(hn1, 4 * k);  \
                _Pragma("unroll")                                          \
                for (int k = 0; k < 9; ++k)                                \
                    hsl[16 + k] = rdlane(hn2, 4 * k);                      \
            }

            #pragma unroll 1
            for (int tt = 0; tt < CHUNK; tt += 2) {
                L2P(0, tt)
                __syncthreads();
                L2C(0)
                L2P(1, tt + 1)
                __syncthreads();
                L2C(1)
            }
            #undef L2P
            #undef L2C
        }

        // epilogue: publish my 25 units' final h2 (hsl is wave-uniform)
        float hv = 0.f;
        #pragma unroll
        for (int j = 0; j < 25; ++j)
            if (lane == j) hv = hsl[j];
        if (lane < 25) s_h2[OFF + lane] = hv;
        __syncthreads();                                // join
    }

    // ---- outputs: result(256,20) @0, last(256,50) @5120 ----
    if (tid < NH2) out[BATCH * NCLS + b * NH2 + tid] = s_h2[tid];
    if (tid < NCLS) {
        float acc = bfc[tid];
        const float* wr = Wfc + tid * NH2;
        #pragma unroll
        for (int j = 0; j < NH2; ++j) acc = fmaf(s_h2[j], wr[j], acc);
        out[b * NCLS + tid] = acc;
    }
}

} // namespace

extern "C" void kernel_launch(void* const* d_in, const int* in_sizes, int n_in,
                              void* d_out, int out_size, void* d_ws, size_t ws_size,
                              hipStream_t stream) {
    (void)in_sizes; (void)n_in; (void)d_ws; (void)ws_size; (void)out_size;
    const float* x    = (const float*)d_in[0];
    const float* W1ih = (const float*)d_in[1];
    const float* W1hh = (const float*)d_in[2];
    const float* b1ih = (const float*)d_in[3];
    const float* b1hh = (const float*)d_in[4];
    const float* W2ih = (const float*)d_in[5];
    const float* W2hh = (const float*)d_in[6];
    const float* b2ih = (const float*)d_in[7];
    const float* b2hh = (const float*)d_in[8];
    const float* Wfc  = (const float*)d_in[9];
    const float* bfc  = (const float*)d_in[10];

    lstm_fused_kernel<<<dim3(BATCH), dim3(192), 0, stream>>>(
        x, W1ih, W1hh, b1ih, b1hh, W2ih, W2hh, b2ih, b2hh, Wfc, bfc,
        (float*)d_out);
}